// Round 1
// baseline (195.601 us; speedup 1.0000x reference)
//
#include <hip/hip_runtime.h>
#include <math.h>

#define B_TOT   1024
#define S_DIM   64
#define N_DIM   256
#define UNFOLDS 12
#define L2E     1.4426950408889634f

#if defined(__has_builtin)
#if __has_builtin(__builtin_amdgcn_exp2f)
#define FEXP2(x) __builtin_amdgcn_exp2f(x)
#endif
#if __has_builtin(__builtin_amdgcn_rcpf)
#define FRCP(x) __builtin_amdgcn_rcpf(x)
#endif
#endif
#ifndef FEXP2
#define FEXP2(x) exp2f(x)
#endif
#ifndef FRCP
#define FRCP(x) (1.0f / (x))
#endif

__device__ __forceinline__ float softplus_f(float x) {
    return log1pf(expf(x));   // inputs all small & bounded; precise form is fine
}

// Pack per-(pre,post) params into float4 {A, B, WE, WEr}:
//   sigmoid(sigma*(v-mu)) = 1 / (1 + exp2(A*v + B)),  A = -L2E*sigma, B = L2E*sigma*mu
//   WE = softplus(w)*mask, WEr = WE*erev
__global__ void ltc_precompute(const float* __restrict__ gleak, const float* __restrict__ vleak,
                               const float* __restrict__ cm,    const float* __restrict__ w,
                               const float* __restrict__ sigma, const float* __restrict__ mu,
                               const float* __restrict__ erev,
                               const float* __restrict__ sw,    const float* __restrict__ ssig,
                               const float* __restrict__ smu,   const float* __restrict__ serev,
                               const float* __restrict__ mask,  const float* __restrict__ smask,
                               float4* __restrict__ p4, float4* __restrict__ s4,
                               float4* __restrict__ pj)
{
    const int idx = blockIdx.x * blockDim.x + threadIdx.x;
    if (idx < N_DIM * N_DIM) {
        float we = softplus_f(w[idx]) * mask[idx];
        float sg = sigma[idx];
        float4 o;
        o.x = -L2E * sg;
        o.y =  L2E * sg * mu[idx];
        o.z =  we;
        o.w =  we * erev[idx];
        p4[idx] = o;
    }
    if (idx < S_DIM * N_DIM) {
        float we = softplus_f(sw[idx]) * smask[idx];
        float sg = ssig[idx];
        float4 o;
        o.x = -L2E * sg;
        o.y =  L2E * sg * smu[idx];
        o.z =  we;
        o.w =  we * serev[idx];
        s4[idx] = o;
    }
    if (idx < N_DIM) {
        float g = softplus_f(gleak[idx]);
        float4 o;
        o.x = softplus_f(cm[idx]) * (float)UNFOLDS;  // cm_t = softplus(cm)/(1/12)
        o.y = g;
        o.z = g * vleak[idx];
        o.w = 0.0f;
        pj[idx] = o;
    }
}

// One block = 4 batch rows. 1024 threads: j = tid&255 (post-neuron), q = tid>>8
// (i-range quarter). 12 unfolds stay in LDS; no grid sync needed.
__global__ __launch_bounds__(1024)
void ltc_main(const float* __restrict__ inputs, const float* __restrict__ state,
              const float4* __restrict__ p4, const float4* __restrict__ s4,
              const float4* __restrict__ pj, float* __restrict__ out)
{
    __shared__ float4 v4[N_DIM];        // v[i] for 4 batches (component = batch)
    __shared__ float4 pnum[4][N_DIM];   // partial numerators [q][j]
    __shared__ float4 pden[4][N_DIM];
    __shared__ float  in_lds[4][S_DIM];

    const int tid = threadIdx.x;
    const int j   = tid & (N_DIM - 1);
    const int q   = tid >> 8;
    const int b0  = blockIdx.x << 2;

    // init v from state: group q loads batch b0+q, coalesced over j
    ((float*)v4)[(j << 2) + q] = state[(b0 + q) * N_DIM + j];

    // stage inputs [4][64]: fully coalesced (== inputs[b0*64 + tid] for tid<256)
    if (tid < 4 * S_DIM) {
        in_lds[tid >> 6][tid & 63] = inputs[b0 * S_DIM + tid];
    }

    // per-j combine constants (only q==0 lanes need them)
    float cmt = 0.f, gl = 0.f, glv = 0.f;
    if (q == 0) {
        float4 c = pj[j];
        cmt = c.x; gl = c.y; glv = c.z;
    }
    __syncthreads();

    // ---- sensory pass (once): partial sums over s in [16q, 16q+16) ----
    {
        float n0=0.f,n1=0.f,n2=0.f,n3=0.f,d0=0.f,d1=0.f,d2=0.f,d3=0.f;
        const int s0 = q << 4;
        #pragma unroll 4
        for (int s = s0; s < s0 + 16; ++s) {
            const float4 p = s4[s * N_DIM + j];
            float e0 = FEXP2(fmaf(p.x, in_lds[0][s], p.y));
            float e1 = FEXP2(fmaf(p.x, in_lds[1][s], p.y));
            float e2 = FEXP2(fmaf(p.x, in_lds[2][s], p.y));
            float e3 = FEXP2(fmaf(p.x, in_lds[3][s], p.y));
            float r0 = FRCP(1.0f + e0);
            float r1 = FRCP(1.0f + e1);
            float r2 = FRCP(1.0f + e2);
            float r3 = FRCP(1.0f + e3);
            n0 = fmaf(p.w, r0, n0); d0 = fmaf(p.z, r0, d0);
            n1 = fmaf(p.w, r1, n1); d1 = fmaf(p.z, r1, d1);
            n2 = fmaf(p.w, r2, n2); d2 = fmaf(p.z, r2, d2);
            n3 = fmaf(p.w, r3, n3); d3 = fmaf(p.z, r3, d3);
        }
        pnum[q][j] = make_float4(n0, n1, n2, n3);
        pden[q][j] = make_float4(d0, d1, d2, d3);
    }
    __syncthreads();

    float4 sn4 = make_float4(0.f, 0.f, 0.f, 0.f);
    float4 sd4 = make_float4(0.f, 0.f, 0.f, 0.f);
    if (q == 0) {
        #pragma unroll
        for (int qq = 0; qq < 4; ++qq) {
            float4 a = pnum[qq][j], b = pden[qq][j];
            sn4.x += a.x; sn4.y += a.y; sn4.z += a.z; sn4.w += a.w;
            sd4.x += b.x; sd4.y += b.y; sd4.z += b.z; sd4.w += b.w;
        }
    }
    __syncthreads();

    // ---- 12 ODE unfolds ----
    const float4* __restrict__ pr = p4 + (q << 6) * N_DIM + j;
    const int vbase = q << 6;

    for (int step = 0; step < UNFOLDS; ++step) {
        float n0=0.f,n1=0.f,n2=0.f,n3=0.f,d0=0.f,d1=0.f,d2=0.f,d3=0.f;
        #pragma unroll 4
        for (int i = 0; i < 64; ++i) {
            const float4 p  = pr[i * N_DIM];     // coalesced dwordx4, L2-resident
            const float4 vv = v4[vbase + i];     // LDS broadcast (same addr all lanes)
            float e0 = FEXP2(fmaf(p.x, vv.x, p.y));
            float e1 = FEXP2(fmaf(p.x, vv.y, p.y));
            float e2 = FEXP2(fmaf(p.x, vv.z, p.y));
            float e3 = FEXP2(fmaf(p.x, vv.w, p.y));
            float r0 = FRCP(1.0f + e0);
            float r1 = FRCP(1.0f + e1);
            float r2 = FRCP(1.0f + e2);
            float r3 = FRCP(1.0f + e3);
            n0 = fmaf(p.w, r0, n0); d0 = fmaf(p.z, r0, d0);
            n1 = fmaf(p.w, r1, n1); d1 = fmaf(p.z, r1, d1);
            n2 = fmaf(p.w, r2, n2); d2 = fmaf(p.z, r2, d2);
            n3 = fmaf(p.w, r3, n3); d3 = fmaf(p.z, r3, d3);
        }
        pnum[q][j] = make_float4(n0, n1, n2, n3);
        pden[q][j] = make_float4(d0, d1, d2, d3);
        __syncthreads();

        if (q == 0) {
            float4 tn = sn4, td = sd4;
            #pragma unroll
            for (int qq = 0; qq < 4; ++qq) {
                float4 a = pnum[qq][j], b = pden[qq][j];
                tn.x += a.x; tn.y += a.y; tn.z += a.z; tn.w += a.w;
                td.x += b.x; td.y += b.y; td.z += b.z; td.w += b.w;
            }
            const float4 vo = v4[j];
            const float cg = cmt + gl + 1e-8f;
            float4 vn;
            vn.x = (fmaf(cmt, vo.x, glv) + tn.x) * FRCP(cg + td.x);
            vn.y = (fmaf(cmt, vo.y, glv) + tn.y) * FRCP(cg + td.y);
            vn.z = (fmaf(cmt, vo.z, glv) + tn.z) * FRCP(cg + td.z);
            vn.w = (fmaf(cmt, vo.w, glv) + tn.w) * FRCP(cg + td.w);
            v4[j] = vn;
        }
        __syncthreads();
    }

    // writeback: group q writes batch b0+q, coalesced over j
    out[(b0 + q) * N_DIM + j] = ((const float*)v4)[(j << 2) + q];
}

extern "C" void kernel_launch(void* const* d_in, const int* in_sizes, int n_in,
                              void* d_out, int out_size, void* d_ws, size_t ws_size,
                              hipStream_t stream)
{
    const float* inputs = (const float*)d_in[0];
    const float* state  = (const float*)d_in[1];
    const float* gleak  = (const float*)d_in[2];
    const float* vleak  = (const float*)d_in[3];
    const float* cm     = (const float*)d_in[4];
    const float* w      = (const float*)d_in[5];
    const float* sigma  = (const float*)d_in[6];
    const float* mu     = (const float*)d_in[7];
    const float* erev   = (const float*)d_in[8];
    const float* sw     = (const float*)d_in[9];
    const float* ssig   = (const float*)d_in[10];
    const float* smu    = (const float*)d_in[11];
    const float* serev  = (const float*)d_in[12];
    const float* mask   = (const float*)d_in[13];
    const float* smask  = (const float*)d_in[14];

    float4* p4 = (float4*)d_ws;                 // [N*N] = 1 MiB
    float4* s4 = p4 + N_DIM * N_DIM;            // [S*N] = 256 KiB
    float4* pj = s4 + S_DIM * N_DIM;            // [N]   = 4 KiB

    ltc_precompute<<<(N_DIM * N_DIM + 255) / 256, 256, 0, stream>>>(
        gleak, vleak, cm, w, sigma, mu, erev, sw, ssig, smu, serev, mask, smask,
        p4, s4, pj);

    ltc_main<<<B_TOT / 4, 1024, 0, stream>>>(inputs, state, p4, s4, pj, (float*)d_out);
}